// Round 3
// baseline (65.074 us; speedup 1.0000x reference)
//
#include <hip/hip_runtime.h>

// y[g,k,n,m] = sum_{i,j} w[i,k,j] * r[m+j],  r[p] = x[g,i,n,(p-2)%7] for
// p in 1..7 else 0;  out[g,k,(n+1)%7,m] = y[g,k,n,m].  (shift==1 folded in)
//
// R9: R8 (512 thr, 2 waves/SIMD, 16-iter loop) = 64.6 us. Kernel term is
// latency-bound (compute ~1.5 us at 157 TF); push occupancy one more notch:
// 1024 threads/block = 64 ic-groups x 16 kL, 8 i per thread.
//   - inner loop halves again (16 -> 8 iters)
//   - 16 waves/CU = 4 waves/SIMD: 2x the latency hiding on w-load + ds_read
//   - grid stays 32 kc x 7 n = 224 balanced blocks, bid%8==kc%8 keeps each
//     w slab on one XCD's L2
// Swizzle moves to +4 floats per 8 rows ((i>>3)<<2): a wave's 4 concurrent
// ic-groups are now 8 rows (96 floats = bank 0) apart; offsets 0/4/8/12
// make them conflict-free, still 16B-aligned, and the +12-float/iter
// advance rotates all groups equally so they stay disjoint.
// Reduction: shfl_xor(16,32) folds the 4 ic-groups per wave, then a
// 16-wave LDS tree.

#define NKC 32
#define KC  16

__device__ __forceinline__ int xrow(int i) {   // swizzled LDS row offset
    return i * 12 + ((i >> 3) << 2);
}

__global__ __launch_bounds__(1024) void conv_one(
    const float* __restrict__ x,   // (1024, 7, 7) = (g*512+i, n, m)
    const float* __restrict__ w,   // (512, 512, 3) = (i, k, j)
    float* __restrict__ out)       // (1024, 7, 7)
{
    // per group: 512 rows x 12 floats (+ swizzle pad): r[p]=x[g,i,n,(p-2)%7]
    __shared__ __align__(16) float x_s[2][512 * 12 + 256];
    __shared__ float red[16][2][16][7];

    const int b   = blockIdx.x;        // 224
    const int kc  = b & 31;            // same-kc blocks -> same XCD (bid%8)
    const int n   = b >> 5;            // 0..6
    const int tid = threadIdx.x;
    const int kL  = tid & 15;
    const int ic  = tid >> 4;          // 0..63, 8 i each

    // ---- stage x[g, :, n, :] for BOTH groups, width-roll folded in ----
    #pragma unroll
    for (int g = 0; g < 2; ++g) {
        const float* xg = x + (size_t)g * 25088 + n * 7;   // [i*49 + m]
        #pragma unroll
        for (int e = tid; e < 512 * 7; e += 1024) {
            const int i  = e / 7;
            const int m  = e % 7;
            const int mm = (m == 6) ? 1 : (m + 2);          // (m+2) mod 7 -> 1..7
            x_s[g][xrow(i) + mm] = xg[i * 49 + m];
        }
        if (tid < 512) {                                    // zero pads p=0,8
            x_s[g][xrow(tid) + 0] = 0.f;
            x_s[g][xrow(tid) + 8] = 0.f;
        }
    }
    __syncthreads();

    // ---- accumulate over this thread's 8 i values, both groups ----
    const int k = kc * KC + kL;
    const float* wp  = w + (size_t)(ic * 8) * 1536 + k * 3;
    const float* xr0 = &x_s[0][xrow(ic * 8)];               // advance 12/iter
    const float* xr1 = &x_s[1][xrow(ic * 8)];

    float a0 = 0.f, a1 = 0.f, a2 = 0.f, a3 = 0.f, a4 = 0.f, a5 = 0.f, a6 = 0.f;
    float b0 = 0.f, b1 = 0.f, b2 = 0.f, b3 = 0.f, b4 = 0.f, b5 = 0.f, b6 = 0.f;

    #pragma unroll
    for (int ii = 0; ii < 8; ++ii) {
        const float w0 = wp[0], w1 = wp[1], w2 = wp[2];
        wp += 1536;
        const float4 ra = *(const float4*)(xr0);            // g0 r[0..3]
        const float4 rb = *(const float4*)(xr0 + 4);        // g0 r[4..7]
        const float  r8 = xr0[8];
        xr0 += 12;
        const float4 sa = *(const float4*)(xr1);            // g1 r[0..3]
        const float4 sb = *(const float4*)(xr1 + 4);        // g1 r[4..7]
        const float  s8 = xr1[8];
        xr1 += 12;

        a0 += w0 * ra.x + w1 * ra.y + w2 * ra.z;
        a1 += w0 * ra.y + w1 * ra.z + w2 * ra.w;
        a2 += w0 * ra.z + w1 * ra.w + w2 * rb.x;
        a3 += w0 * ra.w + w1 * rb.x + w2 * rb.y;
        a4 += w0 * rb.x + w1 * rb.y + w2 * rb.z;
        a5 += w0 * rb.y + w1 * rb.z + w2 * rb.w;
        a6 += w0 * rb.z + w1 * rb.w + w2 * r8;

        b0 += w0 * sa.x + w1 * sa.y + w2 * sa.z;
        b1 += w0 * sa.y + w1 * sa.z + w2 * sa.w;
        b2 += w0 * sa.z + w1 * sa.w + w2 * sb.x;
        b3 += w0 * sa.w + w1 * sb.x + w2 * sb.y;
        b4 += w0 * sb.x + w1 * sb.y + w2 * sb.z;
        b5 += w0 * sb.y + w1 * sb.z + w2 * sb.w;
        b6 += w0 * sb.z + w1 * sb.w + w2 * s8;
    }

    // ---- reduce the 4 ic-groups within each wave (lane bits 4,5) ----
    a0 += __shfl_xor(a0, 16); a0 += __shfl_xor(a0, 32);
    a1 += __shfl_xor(a1, 16); a1 += __shfl_xor(a1, 32);
    a2 += __shfl_xor(a2, 16); a2 += __shfl_xor(a2, 32);
    a3 += __shfl_xor(a3, 16); a3 += __shfl_xor(a3, 32);
    a4 += __shfl_xor(a4, 16); a4 += __shfl_xor(a4, 32);
    a5 += __shfl_xor(a5, 16); a5 += __shfl_xor(a5, 32);
    a6 += __shfl_xor(a6, 16); a6 += __shfl_xor(a6, 32);

    b0 += __shfl_xor(b0, 16); b0 += __shfl_xor(b0, 32);
    b1 += __shfl_xor(b1, 16); b1 += __shfl_xor(b1, 32);
    b2 += __shfl_xor(b2, 16); b2 += __shfl_xor(b2, 32);
    b3 += __shfl_xor(b3, 16); b3 += __shfl_xor(b3, 32);
    b4 += __shfl_xor(b4, 16); b4 += __shfl_xor(b4, 32);
    b5 += __shfl_xor(b5, 16); b5 += __shfl_xor(b5, 32);
    b6 += __shfl_xor(b6, 16); b6 += __shfl_xor(b6, 32);

    const int wave = tid >> 6;          // 0..15
    if ((tid & 63) < 16) {
        red[wave][0][kL][0] = a0; red[wave][0][kL][1] = a1;
        red[wave][0][kL][2] = a2; red[wave][0][kL][3] = a3;
        red[wave][0][kL][4] = a4; red[wave][0][kL][5] = a5;
        red[wave][0][kL][6] = a6;
        red[wave][1][kL][0] = b0; red[wave][1][kL][1] = b1;
        red[wave][1][kL][2] = b2; red[wave][1][kL][3] = b3;
        red[wave][1][kL][4] = b4; red[wave][1][kL][5] = b5;
        red[wave][1][kL][6] = b6;
    }
    __syncthreads();

    // ---- final sum across the 16 waves + store (both groups) ----
    if (tid < 224) {
        const int gg = tid / 112;          // group
        const int r  = tid - gg * 112;
        const int kk = r & 15;             // k within chunk
        const int m  = r >> 4;             // 0..6
        float s = 0.f;
        #pragma unroll
        for (int wv = 0; wv < 16; ++wv) s += red[wv][gg][kk][m];
        const int nOut = (n + 1) % 7;      // final height roll
        out[((size_t)(gg * 512 + kc * KC + kk) * 7 + nOut) * 7 + m] = s;
    }
}

extern "C" void kernel_launch(void* const* d_in, const int* in_sizes, int n_in,
                              void* d_out, int out_size, void* d_ws, size_t ws_size,
                              hipStream_t stream) {
    const float* x = (const float*)d_in[0];
    const float* w = (const float*)d_in[1];
    float* out = (float*)d_out;
    conv_one<<<dim3(NKC * 7), dim3(1024), 0, stream>>>(x, w, out);
}